// Round 3
// baseline (478.704 us; speedup 1.0000x reference)
//
#include <hip/hip_runtime.h>

// NaiveCustomLSTM: V block-diagonal (20 blocks of 32), U (nearly) diagonal.
// => 2560 independent 32-wide LSTMs (128 batch x 20 blocks), 512 steps.
// One wave per unit, one wave per workgroup (grid=2560 -> 10 waves/CU).
// Lanes 0-31: gates i,f for n=lane; lanes 32-63: gates g,o for n=lane-32.
//
// R10 change: hsh widened to 4096 floats = 16 KiB static LDS (only [0..63]
// used). This clamps LDS-limited occupancy to 10 WGs/CU -- EXACTLY the grid's
// 2560/256 -- so nothing is lost at runtime, but the compiler's achievable-
// occupancy computation (which feeds the scheduler's register-pressure
// target) drops from 8 waves/EU to 2-3, raising the VGPR budget to >=170.
// Evidence this is the right lever: R7 (launch_bounds(64,3) -> 72 regs),
// R8 (asm pins -> spilled, 60 regs), R9 (waves_per_eu(2,4) -> 64 regs) all
// failed to stop the scheduler from remat/spilling the ~130-reg working set
// down to 64 arch VGPRs; measured instruction stream was ~148 VALU/step vs
// ~70 in the source (263us @ 60% VALUBusy = 740 issue cyc/SIMD-step).
// Remat exists to buy occupancy; with occupancy LDS-capped it buys nothing,
// so the weights finally stay register-resident.
//
// Also: xa/xb register staging restored (budget now real; removes R9's extra
// 1.1MB FETCH), and each 32-dot split into 2 interleaved pk-fma chains
// (depth 16 -> 8) to shorten the per-step serial dependency chain.
//
// Inner structure otherwise = R9: h broadcast via LDS ds_write_b32 + 8x
// same-address ds_read_b128 (conflict-free); 32x v_pk_fma_f32 = 64 MACs/step.
// Sigmoid/tanh exp2 scales pre-folded per-lane into weights so the
// accumulator IS the exp2 arg. Only raw x (lane-uniform in n) is broadcast
// via readlane; per-lane weights applied after broadcast.

#define TT 512
#define HN 640
#define BN 128

typedef float f2 __attribute__((ext_vector_type(2)));

__device__ __forceinline__ float rl(float v, int s) {
  return __int_as_float(__builtin_amdgcn_readlane(__float_as_int(v), s));
}

__global__ __attribute__((amdgpu_flat_work_group_size(64, 64),
                          amdgpu_waves_per_eu(2, 4)))
void lstm_kernel(
    const float* __restrict__ x,
    const float* __restrict__ Ui, const float* __restrict__ Vi, const float* __restrict__ bi,
    const float* __restrict__ Uf, const float* __restrict__ Vf, const float* __restrict__ bf,
    const float* __restrict__ Uc, const float* __restrict__ Vc, const float* __restrict__ bc,
    const float* __restrict__ Uo, const float* __restrict__ Vo, const float* __restrict__ bo,
    float* __restrict__ out) {
  // 16 KiB static LDS: occupancy clamp (see header). Only [0..63] used:
  // [0..31] valid h, [32..63] junk sink.
  __shared__ __align__(16) float hsh[4096];

  const int unit = blockIdx.x;   // 0..2559
  const int lane = threadIdx.x;  // 0..63
  const int j = unit >> 7;       // hidden block 0..19
  const int b = unit & 127;      // batch
  const int gp = lane >> 5;      // 0: gates i,f ; 1: gates g,o
  const int n = lane & 31;
  const int col = j * 32 + n;

  const float* UG1 = gp ? Uc : Ui;
  const float* UG2 = gp ? Uo : Uf;
  const float* VG1 = gp ? Vc : Vi;
  const float* VG2 = gp ? Vo : Vf;
  const float* bG1 = gp ? bc : bi;
  const float* bG2 = gp ? bo : bf;

  const float LOG2E = 1.44269504088896340736f;
  // gate1: lo = sigmoid(i) (scale -log2e); hi = tanh(g) (scale -2log2e)
  // gate2: sigmoid (f / o) for both halves.
  const float B1 = gp ? (-2.f * LOG2E) : -LOG2E;
  const float B2 = -LOG2E;
  const float Ac1 = gp ? 2.f : 1.f;
  const float Cc1 = gp ? -1.f : 0.f;

  // Effective input weights for this block (from U mask structure).
  float w11 = 0.f, w21 = 0.f, w12 = 0.f, w22 = 0.f;
  int f1 = 0, f2i = 0;
  if (j < 16) {
    f1 = f2i = j;
    w11 = UG1[j * HN + col];
    w12 = UG2[j * HN + col];
    if (j == 0) {
      w11 += UG1[16 * HN + col]; w12 += UG2[16 * HN + col];
      w21  = UG1[17 * HN + col]; w22  = UG2[17 * HN + col];
      f2i = 1;
    } else if (j == 2) {
      w11 += UG1[18 * HN + col]; w12 += UG2[18 * HN + col];
      w21  = UG1[19 * HN + col]; w22  = UG2[19 * HN + col];
      f2i = 3;
    }
  }
  // Pre-scale per-lane input weights/bias by the exp2 factor (stays per-lane).
  const float ws11 = B1 * w11, ws21 = B1 * w21, bs1 = B1 * bG1[col];
  const float ws12 = B2 * w12, ws22 = B2 * w22, bs2 = B2 * bG2[col];

  // Recurrent weight columns, pre-scaled, paired over k:
  // wA[kp] = {B1*V1[2kp,col], B1*V1[2kp+1,col]}, wB likewise with B2*V2.
  f2 wA[16], wB[16];
#pragma unroll
  for (int kp = 0; kp < 16; ++kp) {
    wA[kp].x = B1 * VG1[(j * 32 + 2 * kp) * HN + col];
    wA[kp].y = B1 * VG1[(j * 32 + 2 * kp + 1) * HN + col];
    wB[kp].x = B2 * VG2[(j * 32 + 2 * kp) * HN + col];
    wB[kp].y = B2 * VG2[(j * 32 + 2 * kp + 1) * HN + col];
  }
  // Pin the weights as VGPR-resident (opaque defs: no remat/sinking into loop).
#pragma unroll
  for (int kp = 0; kp < 16; ++kp) {
    asm volatile("" : "+v"(wA[kp]), "+v"(wB[kp]));
  }

  // Stage RAW input sequence in registers (lane-uniform in n: only t varies).
  // Lane holds t = i*64+lane.
  float xa[8], xb[8];
#pragma unroll
  for (int i = 0; i < 8; ++i) {
    const int t = i * 64 + lane;
    xa[i] = x[(b * TT + t) * 16 + f1];
    xb[i] = x[(b * TT + t) * 16 + f2i];
  }
#pragma unroll
  for (int i = 0; i < 8; ++i) {
    asm volatile("" : "+v"(xa[i]), "+v"(xb[i]));
  }

  float h = 0.f, c = 0.f;  // valid in lanes 0-31; upper half carries junk
  int ob = b * TT * HN + col;
#pragma unroll
  for (int i = 0; i < 8; ++i) {
    const float xc1 = xa[i];
    const float xc2 = xb[i];
    for (int s = 0; s < 64; ++s) {
      const float x1 = rl(xc1, s);  // raw x -- safe to broadcast
      const float x2 = rl(xc2, s);
      // Per-lane scaled x-contribution (weights applied AFTER broadcast).
      const float sx1 = fmaf(x2, ws21, fmaf(x1, ws11, bs1));
      const float sx2 = fmaf(x2, ws22, fmaf(x1, ws12, bs2));
      // Broadcast h through LDS. All lanes store (no divergence); only
      // [0..31] is meaningful. Same-wave DS ops execute in order.
      hsh[lane] = h;
      __builtin_amdgcn_wave_barrier();
      f2 hp[16];
      __builtin_memcpy(hp, hsh, 128);  // 8x broadcast ds_read_b128, in place
      __builtin_amdgcn_wave_barrier();
      // Two interleaved pk-fma chains per gate-pair: dep depth 8, not 16.
      f2 aA0 = {sx1, 0.f}, aA1 = {0.f, 0.f};
      f2 aB0 = {sx2, 0.f}, aB1 = {0.f, 0.f};
#pragma unroll
      for (int kp = 0; kp < 16; kp += 2) {
        aA0 = __builtin_elementwise_fma(wA[kp],     hp[kp],     aA0);
        aB0 = __builtin_elementwise_fma(wB[kp],     hp[kp],     aB0);
        aA1 = __builtin_elementwise_fma(wA[kp + 1], hp[kp + 1], aA1);
        aB1 = __builtin_elementwise_fma(wB[kp + 1], hp[kp + 1], aB1);
      }
      const f2 aA = aA0 + aA1;       // v_pk_add_f32
      const f2 aB = aB0 + aB1;
      const float a1 = aA.x + aA.y;  // = B1 * gate1 preactivation
      const float a2 = aB.x + aB.y;  // = B2 * gate2 preactivation
      const float e1 = __builtin_amdgcn_exp2f(a1);
      const float e2 = __builtin_amdgcn_exp2f(a2);
      // lo: g1=sig(i), g2=sig(f); hi: g1=tanh(g), g2=sig(o)
      const float g1 = fmaf(Ac1, __builtin_amdgcn_rcpf(1.f + e1), Cc1);
      const float g2 = __builtin_amdgcn_rcpf(1.f + e2);
      const float p1 = __shfl_xor(g1, 32);  // lo gets tanh(g); hi gets sig(i)
      const float p2 = __shfl_xor(g2, 32);  // lo gets sig(o);  hi gets sig(f)
      c = fmaf(g2, c, g1 * p1);             // lo: c = sig(f)*c + sig(i)*tanh(g)
      const float tc = fmaf(
          2.f,
          __builtin_amdgcn_rcpf(1.f + __builtin_amdgcn_exp2f(-2.f * LOG2E * c)),
          -1.f);
      h = p2 * tc;                          // lo: h = sig(o)*tanh(c)
      if (lane < 32) out[ob] = h;
      ob += HN;
    }
  }
  if (lane < 32) {
    out[BN * TT * HN + b * HN + col] = h;             // h_t
    out[BN * TT * HN + BN * HN + b * HN + col] = c;   // c_t
  }
}

extern "C" void kernel_launch(void* const* d_in, const int* in_sizes, int n_in,
                              void* d_out, int out_size, void* d_ws, size_t ws_size,
                              hipStream_t stream) {
  (void)in_sizes; (void)n_in; (void)d_ws; (void)ws_size; (void)out_size;
  const float* x  = (const float*)d_in[0];
  const float* Ui = (const float*)d_in[1];
  const float* Vi = (const float*)d_in[2];
  const float* bi = (const float*)d_in[3];
  const float* Uf = (const float*)d_in[4];
  const float* Vf = (const float*)d_in[5];
  const float* bf = (const float*)d_in[6];
  const float* Uc = (const float*)d_in[7];
  const float* Vc = (const float*)d_in[8];
  const float* bc = (const float*)d_in[9];
  const float* Uo = (const float*)d_in[10];
  const float* Vo = (const float*)d_in[11];
  const float* bo = (const float*)d_in[12];
  float* out = (float*)d_out;

  dim3 grid(2560);  // one wave per workgroup -> exactly 10 waves/CU, balanced
  dim3 block(64);
  hipLaunchKernelGGL(lstm_kernel, grid, block, 0, stream,
                     x, Ui, Vi, bi, Uf, Vf, bf, Uc, Vc, bc, Uo, Vo, bo, out);
}

// Round 4
// 392.238 us; speedup vs baseline: 1.2204x; 1.2204x over previous
//
#include <hip/hip_runtime.h>

// NaiveCustomLSTM: V block-diagonal (20 blocks of 32), U (nearly) diagonal.
// => 2560 independent 32-wide LSTMs (128 batch x 20 blocks), 512 steps.
// One wave per unit, one wave per workgroup. Lanes 0-31: gates i,f for
// n=lane; lanes 32-63: gates g,o for n=lane-32.
//
// R11: full inline-asm inner loop. R7-R10 established that the gfx950
// scheduler's register-pressure target (max-occupancy-driven) cannot be
// raised from HIP source: launch_bounds(64,3)->72 regs, asm pins->spills,
// waves_per_eu(2,4)->64 regs, 16KB-LDS occupancy clamp->72 regs + WORSE
// runtime occupancy (22%->14.7%). The ~64-reg allocation forces ~80 extra
// issue-cycles/step of remat/reload (measured ~150 instr-equiv vs ~70 in
// source). Fix: the 64-step loop is one asm volatile block; the 32 f2
// V-weight pairs are "v" operands (must be VGPR-resident at the asm, no
// remat possible inside), scratch is explicitly clobbered v36-v86.
//
// Changes vs R10 inner loop (same FP op sequence -> absmax bit-identical):
// - x broadcast via LDS: per 64-chunk, lanes stage raw x into hsh[64..191];
//   per step one ds_read2_b32 (uniform addr = broadcast) replaces 2
//   readlanes (SGPR hazards in asm). Joins the existing lgkm wait;
//   lgkmcnt(8) lets the sx FMAs run under the 8 in-flight b128 reads.
// - per-step h store via buffer_store_dword + SRD (num_records = out bytes);
//   junk lanes 32-63 get voffset 0x60000000 (OOB -> store dropped in HW).
// - next chunk's x global-loads issued before the asm block: ~500 cyc HBM
//   latency hides under the ~15k-cycle chunk.
// - h broadcast unchanged: ds_write_b32 + 8x same-address ds_read_b128.

#define TT 512
#define HN 640
#define BN 128

typedef float f2 __attribute__((ext_vector_type(2)));
typedef unsigned int u32x4 __attribute__((ext_vector_type(4)));

__global__ __attribute__((amdgpu_flat_work_group_size(64, 64)))
void lstm_kernel(
    const float* __restrict__ x,
    const float* __restrict__ Ui, const float* __restrict__ Vi, const float* __restrict__ bi,
    const float* __restrict__ Uf, const float* __restrict__ Vf, const float* __restrict__ bf,
    const float* __restrict__ Uc, const float* __restrict__ Vc, const float* __restrict__ bc,
    const float* __restrict__ Uo, const float* __restrict__ Vo, const float* __restrict__ bo,
    float* __restrict__ out) {
  // [0..63]: h broadcast ([0..31] valid, [32..63] junk sink);
  // [64..127]: x1 for the current 64-step chunk; [128..191]: x2.
  __shared__ __align__(16) float hsh[192];

  const int unit = blockIdx.x;   // 0..2559
  const int lane = threadIdx.x;  // 0..63
  const int j = unit >> 7;       // hidden block 0..19
  const int b = unit & 127;      // batch
  const int gp = lane >> 5;      // 0: gates i,f ; 1: gates g,o
  const int n = lane & 31;
  const int col = j * 32 + n;

  const float* UG1 = gp ? Uc : Ui;
  const float* UG2 = gp ? Uo : Uf;
  const float* VG1 = gp ? Vc : Vi;
  const float* VG2 = gp ? Vo : Vf;
  const float* bG1 = gp ? bc : bi;
  const float* bG2 = gp ? bo : bf;

  const float LOG2E = 1.44269504088896340736f;
  // gate1: lo = sigmoid(i) (scale -log2e); hi = tanh(g) (scale -2log2e)
  // gate2: sigmoid (f / o) for both halves.
  const float B1 = gp ? (-2.f * LOG2E) : -LOG2E;
  const float B2 = -LOG2E;
  const float Ac1 = gp ? 2.f : 1.f;
  const float Cc1 = gp ? -1.f : 0.f;

  // Effective input weights for this block (from U mask structure).
  float w11 = 0.f, w21 = 0.f, w12 = 0.f, w22 = 0.f;
  int f1 = 0, f2i = 0;
  if (j < 16) {
    f1 = f2i = j;
    w11 = UG1[j * HN + col];
    w12 = UG2[j * HN + col];
    if (j == 0) {
      w11 += UG1[16 * HN + col]; w12 += UG2[16 * HN + col];
      w21  = UG1[17 * HN + col]; w22  = UG2[17 * HN + col];
      f2i = 1;
    } else if (j == 2) {
      w11 += UG1[18 * HN + col]; w12 += UG2[18 * HN + col];
      w21  = UG1[19 * HN + col]; w22  = UG2[19 * HN + col];
      f2i = 3;
    }
  }
  // Pre-scale per-lane input weights/bias by the exp2 factor (stays per-lane).
  const float ws11 = B1 * w11, ws21 = B1 * w21, bs1 = B1 * bG1[col];
  const float ws12 = B2 * w12, ws22 = B2 * w22, bs2 = B2 * bG2[col];

  // Recurrent weight columns, pre-scaled, paired over k:
  // wA[kp] = {B1*V1[2kp,col], B1*V1[2kp+1,col]}, wB likewise with B2*V2.
  f2 wA[16], wB[16];
#pragma unroll
  for (int kp = 0; kp < 16; ++kp) {
    wA[kp].x = B1 * VG1[(j * 32 + 2 * kp) * HN + col];
    wA[kp].y = B1 * VG1[(j * 32 + 2 * kp + 1) * HN + col];
    wB[kp].x = B2 * VG2[(j * 32 + 2 * kp) * HN + col];
    wB[kp].y = B2 * VG2[(j * 32 + 2 * kp + 1) * HN + col];
  }

  // LDS byte offsets (low 32 bits of a generic shared address = LDS offset).
  const unsigned zb    = (unsigned)(unsigned long long)&hsh[0];
  const unsigned laddr = zb + (unsigned)lane * 4u;
  const unsigned xbase = zb + 256u;
  const unsigned swz   = (unsigned)((lane ^ 32) & 63) * 4u;  // ds_bpermute sel

  // Buffer SRD over the whole out buffer; junk lanes store OOB (dropped).
  const unsigned out_bytes = (unsigned)((BN * TT * HN + 2 * BN * HN) * 4);
  const unsigned long long outa = (unsigned long long)out;
  u32x4 srd;
  srd.x = (unsigned)outa;
  srd.y = (unsigned)(outa >> 32);
  srd.z = out_bytes;
  srd.w = 0x00020000u;
  unsigned voff = (lane < 32) ? (unsigned)((b * TT * HN + col) * 4)
                              : 0x60000000u;  // far beyond num_records

  float h = 0.f, c = 0.f;  // valid in lanes 0-31; upper half carries junk

  // Prime first chunk's x (lane-uniform in n: only t = i*64+lane varies).
  float nx1 = x[(b * TT + lane) * 16 + f1];
  float nx2 = x[(b * TT + lane) * 16 + f2i];

#pragma unroll 1
  for (int i = 0; i < 8; ++i) {
    hsh[64 + lane]  = nx1;   // stage this chunk's x for broadcast reads
    hsh[128 + lane] = nx2;
    if (i < 7) {  // prefetch next chunk's x; latency hides under the asm
      const int t = (i + 1) * 64 + lane;
      nx1 = x[(b * TT + t) * 16 + f1];
      nx2 = x[(b * TT + t) * 16 + f2i];
    }
    unsigned xaddr = xbase;
    asm volatile(
      "s_mov_b32 s20, 64\n\t"
      "Lstep%=:\n\t"
      // --- broadcast h + this step's x through LDS (same-wave, in-order) ---
      "ds_write_b32 %[laddr], %[h]\n\t"
      "ds_read2_b32 v[38:39], %[xaddr] offset0:0 offset1:64\n\t"
      "ds_read_b128 v[48:51], %[zb]\n\t"
      "ds_read_b128 v[52:55], %[zb] offset:16\n\t"
      "ds_read_b128 v[56:59], %[zb] offset:32\n\t"
      "ds_read_b128 v[60:63], %[zb] offset:48\n\t"
      "ds_read_b128 v[64:67], %[zb] offset:64\n\t"
      "ds_read_b128 v[68:71], %[zb] offset:80\n\t"
      "ds_read_b128 v[72:75], %[zb] offset:96\n\t"
      "ds_read_b128 v[76:79], %[zb] offset:112\n\t"
      "v_add_u32 %[xaddr], 4, %[xaddr]\n\t"
      // wait for write+read2 only; sx math runs under the b128 reads
      "s_waitcnt lgkmcnt(8)\n\t"
      "v_mov_b32 v36, %[bs1]\n\t"
      "v_fmac_f32 v36, v38, %[w11]\n\t"
      "v_fmac_f32 v36, v39, %[w21]\n\t"
      "v_mov_b32 v37, %[bs2]\n\t"
      "v_fmac_f32 v37, v38, %[w12]\n\t"
      "v_fmac_f32 v37, v39, %[w22]\n\t"
      // seed 4 accumulator chains: aA0={sx1,0} aA1=0 aB0={sx2,0} aB1=0
      "v_mov_b32 v40, v36\n\t"
      "v_mov_b32 v41, 0\n\t"
      "v_mov_b32 v42, 0\n\t"
      "v_mov_b32 v43, 0\n\t"
      "v_mov_b32 v44, v37\n\t"
      "v_mov_b32 v45, 0\n\t"
      "v_mov_b32 v46, 0\n\t"
      "v_mov_b32 v47, 0\n\t"
      "s_waitcnt lgkmcnt(0)\n\t"
      // --- 32x v_pk_fma_f32: 64 MACs, 4 interleaved chains (depth 8) ---
      "v_pk_fma_f32 v[40:41], %[wa0],  v[48:49], v[40:41]\n\t"
      "v_pk_fma_f32 v[44:45], %[wb0],  v[48:49], v[44:45]\n\t"
      "v_pk_fma_f32 v[42:43], %[wa1],  v[50:51], v[42:43]\n\t"
      "v_pk_fma_f32 v[46:47], %[wb1],  v[50:51], v[46:47]\n\t"
      "v_pk_fma_f32 v[40:41], %[wa2],  v[52:53], v[40:41]\n\t"
      "v_pk_fma_f32 v[44:45], %[wb2],  v[52:53], v[44:45]\n\t"
      "v_pk_fma_f32 v[42:43], %[wa3],  v[54:55], v[42:43]\n\t"
      "v_pk_fma_f32 v[46:47], %[wb3],  v[54:55], v[46:47]\n\t"
      "v_pk_fma_f32 v[40:41], %[wa4],  v[56:57], v[40:41]\n\t"
      "v_pk_fma_f32 v[44:45], %[wb4],  v[56:57], v[44:45]\n\t"
      "v_pk_fma_f32 v[42:43], %[wa5],  v[58:59], v[42:43]\n\t"
      "v_pk_fma_f32 v[46:47], %[wb5],  v[58:59], v[46:47]\n\t"
      "v_pk_fma_f32 v[40:41], %[wa6],  v[60:61], v[40:41]\n\t"
      "v_pk_fma_f32 v[44:45], %[wb6],  v[60:61], v[44:45]\n\t"
      "v_pk_fma_f32 v[42:43], %[wa7],  v[62:63], v[42:43]\n\t"
      "v_pk_fma_f32 v[46:47], %[wb7],  v[62:63], v[46:47]\n\t"
      "v_pk_fma_f32 v[40:41], %[wa8],  v[64:65], v[40:41]\n\t"
      "v_pk_fma_f32 v[44:45], %[wb8],  v[64:65], v[44:45]\n\t"
      "v_pk_fma_f32 v[42:43], %[wa9],  v[66:67], v[42:43]\n\t"
      "v_pk_fma_f32 v[46:47], %[wb9],  v[66:67], v[46:47]\n\t"
      "v_pk_fma_f32 v[40:41], %[wa10], v[68:69], v[40:41]\n\t"
      "v_pk_fma_f32 v[44:45], %[wb10], v[68:69], v[44:45]\n\t"
      "v_pk_fma_f32 v[42:43], %[wa11], v[70:71], v[42:43]\n\t"
      "v_pk_fma_f32 v[46:47], %[wb11], v[70:71], v[46:47]\n\t"
      "v_pk_fma_f32 v[40:41], %[wa12], v[72:73], v[40:41]\n\t"
      "v_pk_fma_f32 v[44:45], %[wb12], v[72:73], v[44:45]\n\t"
      "v_pk_fma_f32 v[42:43], %[wa13], v[74:75], v[42:43]\n\t"
      "v_pk_fma_f32 v[46:47], %[wb13], v[74:75], v[46:47]\n\t"
      "v_pk_fma_f32 v[40:41], %[wa14], v[76:77], v[40:41]\n\t"
      "v_pk_fma_f32 v[44:45], %[wb14], v[76:77], v[44:45]\n\t"
      "v_pk_fma_f32 v[42:43], %[wa15], v[78:79], v[42:43]\n\t"
      "v_pk_fma_f32 v[46:47], %[wb15], v[78:79], v[46:47]\n\t"
      // --- horizontal reduce + activations (same op order as C++ version) ---
      "v_pk_add_f32 v[40:41], v[40:41], v[42:43]\n\t"
      "v_pk_add_f32 v[44:45], v[44:45], v[46:47]\n\t"
      "v_add_f32 v81, v40, v41\n\t"
      "v_add_f32 v82, v44, v45\n\t"
      "v_exp_f32 v81, v81\n\t"
      "v_exp_f32 v82, v82\n\t"
      "s_nop 1\n\t"
      "v_add_f32 v81, 1.0, v81\n\t"
      "v_add_f32 v82, 1.0, v82\n\t"
      "v_rcp_f32 v81, v81\n\t"
      "v_rcp_f32 v82, v82\n\t"
      "s_nop 1\n\t"
      "v_fma_f32 v81, %[ac1], v81, %[cc1]\n\t"   // g1
      // cross-half exchange (shfl_xor 32)
      "ds_bpermute_b32 v83, %[swz], v81\n\t"     // p1
      "ds_bpermute_b32 v84, %[swz], v82\n\t"     // p2
      "s_waitcnt lgkmcnt(0)\n\t"
      "v_mul_f32 v85, v81, v83\n\t"              // g1*p1
      "v_fma_f32 %[c], v82, %[c], v85\n\t"       // c = g2*c + g1*p1
      "v_mul_f32 v86, 0xc038aa3b, %[c]\n\t"      // -2*log2e * c
      "v_exp_f32 v86, v86\n\t"
      "s_nop 1\n\t"
      "v_add_f32 v86, 1.0, v86\n\t"
      "v_rcp_f32 v86, v86\n\t"
      "s_nop 1\n\t"
      "v_fma_f32 v86, 2.0, v86, -1.0\n\t"        // tanh(c)
      "v_mul_f32 %[h], v84, v86\n\t"             // h = p2 * tanh(c)
      // per-step store; junk lanes OOB -> dropped by SRD bounds check
      "buffer_store_dword %[h], %[voff], %[srd], 0 offen\n\t"
      "v_add_u32 %[voff], 0xa00, %[voff]\n\t"
      "s_sub_u32 s20, s20, 1\n\t"
      "s_cmp_lg_u32 s20, 0\n\t"
      "s_cbranch_scc1 Lstep%=\n\t"
      : [h]"+v"(h), [c]"+v"(c), [voff]"+v"(voff), [xaddr]"+v"(xaddr)
      : [laddr]"v"(laddr), [zb]"v"(zb), [swz]"v"(swz),
        [w11]"v"(ws11), [w21]"v"(ws21), [bs1]"v"(bs1),
        [w12]"v"(ws12), [w22]"v"(ws22), [bs2]"v"(bs2),
        [ac1]"v"(Ac1), [cc1]"v"(Cc1), [srd]"s"(srd),
        [wa0]"v"(wA[0]),  [wa1]"v"(wA[1]),  [wa2]"v"(wA[2]),  [wa3]"v"(wA[3]),
        [wa4]"v"(wA[4]),  [wa5]"v"(wA[5]),  [wa6]"v"(wA[6]),  [wa7]"v"(wA[7]),
        [wa8]"v"(wA[8]),  [wa9]"v"(wA[9]),  [wa10]"v"(wA[10]),[wa11]"v"(wA[11]),
        [wa12]"v"(wA[12]),[wa13]"v"(wA[13]),[wa14]"v"(wA[14]),[wa15]"v"(wA[15]),
        [wb0]"v"(wB[0]),  [wb1]"v"(wB[1]),  [wb2]"v"(wB[2]),  [wb3]"v"(wB[3]),
        [wb4]"v"(wB[4]),  [wb5]"v"(wB[5]),  [wb6]"v"(wB[6]),  [wb7]"v"(wB[7]),
        [wb8]"v"(wB[8]),  [wb9]"v"(wB[9]),  [wb10]"v"(wB[10]),[wb11]"v"(wB[11]),
        [wb12]"v"(wB[12]),[wb13]"v"(wB[13]),[wb14]"v"(wB[14]),[wb15]"v"(wB[15])
      : "memory", "scc", "s20",
        "v36","v37","v38","v39","v40","v41","v42","v43","v44","v45","v46",
        "v47","v48","v49","v50","v51","v52","v53","v54","v55","v56","v57",
        "v58","v59","v60","v61","v62","v63","v64","v65","v66","v67","v68",
        "v69","v70","v71","v72","v73","v74","v75","v76","v77","v78","v79",
        "v81","v82","v83","v84","v85","v86");
  }

  if (lane < 32) {
    out[BN * TT * HN + b * HN + col] = h;             // h_t
    out[BN * TT * HN + BN * HN + b * HN + col] = c;   // c_t
  }
}

extern "C" void kernel_launch(void* const* d_in, const int* in_sizes, int n_in,
                              void* d_out, int out_size, void* d_ws, size_t ws_size,
                              hipStream_t stream) {
  (void)in_sizes; (void)n_in; (void)d_ws; (void)ws_size; (void)out_size;
  const float* x  = (const float*)d_in[0];
  const float* Ui = (const float*)d_in[1];
  const float* Vi = (const float*)d_in[2];
  const float* bi = (const float*)d_in[3];
  const float* Uf = (const float*)d_in[4];
  const float* Vf = (const float*)d_in[5];
  const float* bf = (const float*)d_in[6];
  const float* Uc = (const float*)d_in[7];
  const float* Vc = (const float*)d_in[8];
  const float* bc = (const float*)d_in[9];
  const float* Uo = (const float*)d_in[10];
  const float* Vo = (const float*)d_in[11];
  const float* bo = (const float*)d_in[12];
  float* out = (float*)d_out;

  dim3 grid(2560);  // one wave per workgroup -> 10 waves/CU, balanced
  dim3 block(64);
  hipLaunchKernelGGL(lstm_kernel, grid, block, 0, stream,
                     x, Ui, Vi, bi, Uf, Vf, bf, Uc, Vc, bc, Uo, Vo, bo, out);
}

// Round 5
// 390.445 us; speedup vs baseline: 1.2260x; 1.0046x over previous
//
#include <hip/hip_runtime.h>

// NaiveCustomLSTM: V block-diagonal (20 blocks of 32), U (nearly) diagonal.
// => 2560 independent 32-wide LSTMs (128 batch x 20 blocks), 512 steps.
//
// R12: TWO units per wave (64 lanes = 2 batches x 32 cols, same j-block);
// each lane computes ALL FOUR gates for its (b,n) in-lane.
// Rationale (R11 post-mortem): R11's exact asm stream (65 VALU + 12 DS) ran
// at the same 272us as R7's ~150-instr stream -> not VALU-issue-bound.
// Arithmetic: 1278 cyc/SIMD-step wall; VALU busy 322/wave-step -> v_exp/v_rcp
// ~32 cyc each (wave64 quarter-rate); 2x ds_bpermute ~120cyc latency on the
// serial chain; LDS pipe per CU ~1200 cyc/step (10 waves x ~120) saturated.
// 2-units/wave: eliminates bpermutes (all gates in-lane), trans per unit
// 6->5 (tanh(c) not duplicated), LDS broadcast per unit halved (one 8x
// ds_read_b128 serves 2 units; lo/hi halves read their batch's h block --
// 2-way same-address groups, conflict-free).
// Weights: 128 VGPRs/lane (4 gates x 32 cols), loaded in the asm prologue
// from LDS staging into fixed v96-v223 (allocator untouchable; operand count
// stays at 18). Gate-packed MACs: v_pk_fma_f32 {i,f} and {g,o} streams with
// op_sel broadcasting h[k] into both halves. Grid 1280 (1.25 waves/SIMD);
// VGPR ~230 still allows 2 waves/SIMD.

#define TT 512
#define HN 640
#define BN 128

typedef float f2 __attribute__((ext_vector_type(2)));
typedef unsigned int u32x4 __attribute__((ext_vector_type(4)));

__global__ __attribute__((amdgpu_flat_work_group_size(64, 64)))
void lstm_kernel(
    const float* __restrict__ x,
    const float* __restrict__ Ui, const float* __restrict__ Vi, const float* __restrict__ bi,
    const float* __restrict__ Uf, const float* __restrict__ Vf, const float* __restrict__ bf,
    const float* __restrict__ Uc, const float* __restrict__ Vc, const float* __restrict__ bc,
    const float* __restrict__ Uo, const float* __restrict__ Vo, const float* __restrict__ bo,
    float* __restrict__ out) {
  // LDS layout (bytes): [0..16895] weights: 32 cols x 528B (132 floats; 4
  // floats per k: {Bi*Vi, Bf*Vf, Bg*Vc, Bo*Vo}[k], 528 stride avoids 32-way
  // bank conflict on the prologue b128 reads). [16896..17151] h (64 floats:
  // lanes 0-31 = batch b0, 32-63 = b1). [17152..18175] x stage: 4 x 64
  // floats {x1b0, x2b0, x1b1, x2b1} for the current 64-step chunk.
  __shared__ __align__(16) float lds[4544];

  const int unit = blockIdx.x;   // 0..1279
  const int lane = threadIdx.x;  // 0..63
  const int j  = unit >> 6;      // hidden block 0..19
  const int bp = unit & 63;      // batch pair
  const int gp = lane >> 5;      // 0: batch 2bp ; 1: batch 2bp+1
  const int n  = lane & 31;
  const int col = j * 32 + n;
  const int b  = bp * 2 + gp;

  const float LOG2E = 1.44269504088896340736f;
  const float Bs = -LOG2E;        // sigmoid gates (i, f, o)
  const float Bg = -2.f * LOG2E;  // tanh gate (g)

  // Stage pre-scaled V-weight columns in LDS (lanes 0-31; hi lanes dup cols).
  if (lane < 32) {
    for (int k = 0; k < 32; ++k) {
      const int r = (j * 32 + k) * HN + col;
      lds[n * 132 + k * 4 + 0] = Bs * Vi[r];
      lds[n * 132 + k * 4 + 1] = Bs * Vf[r];
      lds[n * 132 + k * 4 + 2] = Bg * Vc[r];
      lds[n * 132 + k * 4 + 3] = Bs * Vo[r];
    }
  }

  // Effective input weights per gate (U mask structure), features f1, f2i.
  int f1 = 0, f2i = 0;
  if (j < 16) { f1 = f2i = j; if (j == 0) f2i = 1; else if (j == 2) f2i = 3; }
  auto uw = [&](const float* __restrict__ U, float& w1, float& w2) {
    w1 = 0.f; w2 = 0.f;
    if (j < 16) {
      w1 = U[j * HN + col];
      if (j == 0)      { w1 += U[16 * HN + col]; w2 = U[17 * HN + col]; }
      else if (j == 2) { w1 += U[18 * HN + col]; w2 = U[19 * HN + col]; }
    }
  };
  float wi1, wi2, wf1, wf2, wg1, wg2, wo1, wo2;
  uw(Ui, wi1, wi2); uw(Uf, wf1, wf2); uw(Uc, wg1, wg2); uw(Uo, wo1, wo2);
  const f2 w11IF = {Bs * wi1, Bs * wf1}, w21IF = {Bs * wi2, Bs * wf2};
  const f2 w11GO = {Bg * wg1, Bs * wo1}, w21GO = {Bg * wg2, Bs * wo2};
  const f2 bsIF  = {Bs * bi[col], Bs * bf[col]};
  const f2 bsGO  = {Bg * bc[col], Bs * bo[col]};

  // LDS byte addresses (low 32 bits of a shared pointer = LDS offset).
  const unsigned zb    = (unsigned)(unsigned long long)&lds[0];
  const unsigned wrd   = zb + (unsigned)n * 528u;          // weight reads
  const unsigned laddr = zb + 16896u + (unsigned)lane * 4u; // h write
  const unsigned hrd   = zb + 16896u + (unsigned)gp * 128u; // h reads
  const unsigned xw    = zb + 17152u + (unsigned)lane * 4u; // x stage write
  const unsigned xrb   = zb + 17152u + (unsigned)gp * 512u; // x read base

  // SRDs: x (bounds-checked; last-chunk prefetch reads OOB -> returns 0,
  // unused) and out (per-step h stores).
  u32x4 xsrd, osrd;
  { const unsigned long long a = (unsigned long long)x;
    xsrd.x = (unsigned)a; xsrd.y = (unsigned)(a >> 32);
    xsrd.z = (unsigned)(BN * TT * 16 * 4); xsrd.w = 0x00020000u; }
  { const unsigned long long a = (unsigned long long)out;
    osrd.x = (unsigned)a; osrd.y = (unsigned)(a >> 32);
    osrd.z = (unsigned)((BN * TT * HN + 2 * BN * HN) * 4); osrd.w = 0x00020000u; }

  unsigned voff  = (unsigned)((b * TT * HN + col) * 4);
  unsigned xvoff = (unsigned)((((bp * 2) * TT + lane) * 16 + f1) * 4);
  const int sfd  = (f2i - f1) * 4;

  float h = 0.f, c = 0.f;

  asm volatile(
    // ---- prologue: weights LDS->v[96:223]; x chunk-0 loads ----
    "s_waitcnt lgkmcnt(0)\n\t"
    "ds_read_b128 v[96:99],   %[wrd]\n\t"
    "ds_read_b128 v[100:103], %[wrd] offset:16\n\t"
    "ds_read_b128 v[104:107], %[wrd] offset:32\n\t"
    "ds_read_b128 v[108:111], %[wrd] offset:48\n\t"
    "ds_read_b128 v[112:115], %[wrd] offset:64\n\t"
    "ds_read_b128 v[116:119], %[wrd] offset:80\n\t"
    "ds_read_b128 v[120:123], %[wrd] offset:96\n\t"
    "ds_read_b128 v[124:127], %[wrd] offset:112\n\t"
    "ds_read_b128 v[128:131], %[wrd] offset:128\n\t"
    "ds_read_b128 v[132:135], %[wrd] offset:144\n\t"
    "ds_read_b128 v[136:139], %[wrd] offset:160\n\t"
    "ds_read_b128 v[140:143], %[wrd] offset:176\n\t"
    "ds_read_b128 v[144:147], %[wrd] offset:192\n\t"
    "ds_read_b128 v[148:151], %[wrd] offset:208\n\t"
    "ds_read_b128 v[152:155], %[wrd] offset:224\n\t"
    "ds_read_b128 v[156:159], %[wrd] offset:240\n\t"
    "ds_read_b128 v[160:163], %[wrd] offset:256\n\t"
    "ds_read_b128 v[164:167], %[wrd] offset:272\n\t"
    "ds_read_b128 v[168:171], %[wrd] offset:288\n\t"
    "ds_read_b128 v[172:175], %[wrd] offset:304\n\t"
    "ds_read_b128 v[176:179], %[wrd] offset:320\n\t"
    "ds_read_b128 v[180:183], %[wrd] offset:336\n\t"
    "ds_read_b128 v[184:187], %[wrd] offset:352\n\t"
    "ds_read_b128 v[188:191], %[wrd] offset:368\n\t"
    "ds_read_b128 v[192:195], %[wrd] offset:384\n\t"
    "ds_read_b128 v[196:199], %[wrd] offset:400\n\t"
    "ds_read_b128 v[200:203], %[wrd] offset:416\n\t"
    "ds_read_b128 v[204:207], %[wrd] offset:432\n\t"
    "ds_read_b128 v[208:211], %[wrd] offset:448\n\t"
    "ds_read_b128 v[212:215], %[wrd] offset:464\n\t"
    "ds_read_b128 v[216:219], %[wrd] offset:480\n\t"
    "ds_read_b128 v[220:223], %[wrd] offset:496\n\t"
    "s_mov_b32 s22, 0x8000\n\t"
    "s_add_u32 s23, s22, %[sfd]\n\t"
    "buffer_load_dword v36, %[xvoff], %[xsrd], 0 offen\n\t"
    "buffer_load_dword v37, %[xvoff], %[xsrd], %[sfd] offen\n\t"
    "buffer_load_dword v38, %[xvoff], %[xsrd], s22 offen\n\t"
    "buffer_load_dword v39, %[xvoff], %[xsrd], s23 offen\n\t"
    "s_mov_b32 s21, 8\n\t"
    "Lchunk%=:\n\t"
    // stage this chunk's x; prefetch next chunk's
    "s_waitcnt vmcnt(0)\n\t"
    "ds_write_b32 %[xw], v36\n\t"
    "ds_write_b32 %[xw], v37 offset:256\n\t"
    "ds_write_b32 %[xw], v38 offset:512\n\t"
    "ds_write_b32 %[xw], v39 offset:768\n\t"
    "v_add_u32 %[xvoff], 0x1000, %[xvoff]\n\t"
    "buffer_load_dword v36, %[xvoff], %[xsrd], 0 offen\n\t"
    "buffer_load_dword v37, %[xvoff], %[xsrd], %[sfd] offen\n\t"
    "buffer_load_dword v38, %[xvoff], %[xsrd], s22 offen\n\t"
    "buffer_load_dword v39, %[xvoff], %[xsrd], s23 offen\n\t"
    "v_mov_b32 v33, %[xrb]\n\t"
    "s_mov_b32 s20, 64\n\t"
    "Lstep%=:\n\t"
    // h + x broadcast through LDS (same-wave DS ops execute in order)
    "ds_write_b32 %[laddr], %[h]\n\t"
    "ds_read2_b32 v[88:89], v33 offset0:0 offset1:64\n\t"
    "ds_read_b128 v[48:51], %[hrd]\n\t"
    "ds_read_b128 v[52:55], %[hrd] offset:16\n\t"
    "ds_read_b128 v[56:59], %[hrd] offset:32\n\t"
    "ds_read_b128 v[60:63], %[hrd] offset:48\n\t"
    "ds_read_b128 v[64:67], %[hrd] offset:64\n\t"
    "ds_read_b128 v[68:71], %[hrd] offset:80\n\t"
    "ds_read_b128 v[72:75], %[hrd] offset:96\n\t"
    "ds_read_b128 v[76:79], %[hrd] offset:112\n\t"
    "v_add_u32 v33, 4, v33\n\t"
    "s_waitcnt lgkmcnt(8)\n\t"
    // seeds: accIF0 = bsIF + x1*w11IF + x2*w21IF ; accGO0 likewise; acc*1 = 0
    "v_pk_fma_f32 v[40:41], v[88:89], %[w11IF], %[bsIF] op_sel:[0,0,0] op_sel_hi:[0,1,1]\n\t"
    "v_pk_fma_f32 v[44:45], v[88:89], %[w11GO], %[bsGO] op_sel:[0,0,0] op_sel_hi:[0,1,1]\n\t"
    "v_pk_fma_f32 v[40:41], v[88:89], %[w21IF], v[40:41] op_sel:[1,0,0] op_sel_hi:[1,1,1]\n\t"
    "v_pk_fma_f32 v[44:45], v[88:89], %[w21GO], v[44:45] op_sel:[1,0,0] op_sel_hi:[1,1,1]\n\t"
    "v_mov_b32 v42, 0\n\t"
    "v_mov_b32 v43, 0\n\t"
    "v_mov_b32 v46, 0\n\t"
    "v_mov_b32 v47, 0\n\t"
    "s_waitcnt lgkmcnt(0)\n\t"
    // 64x v_pk_fma_f32: k=0..31, streams {i,f} (v40-43) and {g,o} (v44-47),
    // h[k] broadcast into both halves via op_sel; 2 chains/stream (depth 16)
    "v_pk_fma_f32 v[40:41], v[96:97],   v[48:49], v[40:41] op_sel:[0,0,0] op_sel_hi:[1,0,1]\n\t"
    "v_pk_fma_f32 v[44:45], v[98:99],   v[48:49], v[44:45] op_sel:[0,0,0] op_sel_hi:[1,0,1]\n\t"
    "v_pk_fma_f32 v[42:43], v[100:101], v[48:49], v[42:43] op_sel:[0,1,0] op_sel_hi:[1,1,1]\n\t"
    "v_pk_fma_f32 v[46:47], v[102:103], v[48:49], v[46:47] op_sel:[0,1,0] op_sel_hi:[1,1,1]\n\t"
    "v_pk_fma_f32 v[40:41], v[104:105], v[50:51], v[40:41] op_sel:[0,0,0] op_sel_hi:[1,0,1]\n\t"
    "v_pk_fma_f32 v[44:45], v[106:107], v[50:51], v[44:45] op_sel:[0,0,0] op_sel_hi:[1,0,1]\n\t"
    "v_pk_fma_f32 v[42:43], v[108:109], v[50:51], v[42:43] op_sel:[0,1,0] op_sel_hi:[1,1,1]\n\t"
    "v_pk_fma_f32 v[46:47], v[110:111], v[50:51], v[46:47] op_sel:[0,1,0] op_sel_hi:[1,1,1]\n\t"
    "v_pk_fma_f32 v[40:41], v[112:113], v[52:53], v[40:41] op_sel:[0,0,0] op_sel_hi:[1,0,1]\n\t"
    "v_pk_fma_f32 v[44:45], v[114:115], v[52:53], v[44:45] op_sel:[0,0,0] op_sel_hi:[1,0,1]\n\t"
    "v_pk_fma_f32 v[42:43], v[116:117], v[52:53], v[42:43] op_sel:[0,1,0] op_sel_hi:[1,1,1]\n\t"
    "v_pk_fma_f32 v[46:47], v[118:119], v[52:53], v[46:47] op_sel:[0,1,0] op_sel_hi:[1,1,1]\n\t"
    "v_pk_fma_f32 v[40:41], v[120:121], v[54:55], v[40:41] op_sel:[0,0,0] op_sel_hi:[1,0,1]\n\t"
    "v_pk_fma_f32 v[44:45], v[122:123], v[54:55], v[44:45] op_sel:[0,0,0] op_sel_hi:[1,0,1]\n\t"
    "v_pk_fma_f32 v[42:43], v[124:125], v[54:55], v[42:43] op_sel:[0,1,0] op_sel_hi:[1,1,1]\n\t"
    "v_pk_fma_f32 v[46:47], v[126:127], v[54:55], v[46:47] op_sel:[0,1,0] op_sel_hi:[1,1,1]\n\t"
    "v_pk_fma_f32 v[40:41], v[128:129], v[56:57], v[40:41] op_sel:[0,0,0] op_sel_hi:[1,0,1]\n\t"
    "v_pk_fma_f32 v[44:45], v[130:131], v[56:57], v[44:45] op_sel:[0,0,0] op_sel_hi:[1,0,1]\n\t"
    "v_pk_fma_f32 v[42:43], v[132:133], v[56:57], v[42:43] op_sel:[0,1,0] op_sel_hi:[1,1,1]\n\t"
    "v_pk_fma_f32 v[46:47], v[134:135], v[56:57], v[46:47] op_sel:[0,1,0] op_sel_hi:[1,1,1]\n\t"
    "v_pk_fma_f32 v[40:41], v[136:137], v[58:59], v[40:41] op_sel:[0,0,0] op_sel_hi:[1,0,1]\n\t"
    "v_pk_fma_f32 v[44:45], v[138:139], v[58:59], v[44:45] op_sel:[0,0,0] op_sel_hi:[1,0,1]\n\t"
    "v_pk_fma_f32 v[42:43], v[140:141], v[58:59], v[42:43] op_sel:[0,1,0] op_sel_hi:[1,1,1]\n\t"
    "v_pk_fma_f32 v[46:47], v[142:143], v[58:59], v[46:47] op_sel:[0,1,0] op_sel_hi:[1,1,1]\n\t"
    "v_pk_fma_f32 v[40:41], v[144:145], v[60:61], v[40:41] op_sel:[0,0,0] op_sel_hi:[1,0,1]\n\t"
    "v_pk_fma_f32 v[44:45], v[146:147], v[60:61], v[44:45] op_sel:[0,0,0] op_sel_hi:[1,0,1]\n\t"
    "v_pk_fma_f32 v[42:43], v[148:149], v[60:61], v[42:43] op_sel:[0,1,0] op_sel_hi:[1,1,1]\n\t"
    "v_pk_fma_f32 v[46:47], v[150:151], v[60:61], v[46:47] op_sel:[0,1,0] op_sel_hi:[1,1,1]\n\t"
    "v_pk_fma_f32 v[40:41], v[152:153], v[62:63], v[40:41] op_sel:[0,0,0] op_sel_hi:[1,0,1]\n\t"
    "v_pk_fma_f32 v[44:45], v[154:155], v[62:63], v[44:45] op_sel:[0,0,0] op_sel_hi:[1,0,1]\n\t"
    "v_pk_fma_f32 v[42:43], v[156:157], v[62:63], v[42:43] op_sel:[0,1,0] op_sel_hi:[1,1,1]\n\t"
    "v_pk_fma_f32 v[46:47], v[158:159], v[62:63], v[46:47] op_sel:[0,1,0] op_sel_hi:[1,1,1]\n\t"
    "v_pk_fma_f32 v[40:41], v[160:161], v[64:65], v[40:41] op_sel:[0,0,0] op_sel_hi:[1,0,1]\n\t"
    "v_pk_fma_f32 v[44:45], v[162:163], v[64:65], v[44:45] op_sel:[0,0,0] op_sel_hi:[1,0,1]\n\t"
    "v_pk_fma_f32 v[42:43], v[164:165], v[64:65], v[42:43] op_sel:[0,1,0] op_sel_hi:[1,1,1]\n\t"
    "v_pk_fma_f32 v[46:47], v[166:167], v[64:65], v[46:47] op_sel:[0,1,0] op_sel_hi:[1,1,1]\n\t"
    "v_pk_fma_f32 v[40:41], v[168:169], v[66:67], v[40:41] op_sel:[0,0,0] op_sel_hi:[1,0,1]\n\t"
    "v_pk_fma_f32 v[44:45], v[170:171], v[66:67], v[44:45] op_sel:[0,0,0] op_sel_hi:[1,0,1]\n\t"
    "v_pk_fma_f32 v[42:43], v[172:173], v[66:67], v[42:43] op_sel:[0,1,0] op_sel_hi:[1,1,1]\n\t"
    "v_pk_fma_f32 v[46:47], v[174:175], v[66:67], v[46:47] op_sel:[0,1,0] op_sel_hi:[1,1,1]\n\t"
    "v_pk_fma_f32 v[40:41], v[176:177], v[68:69], v[40:41] op_sel:[0,0,0] op_sel_hi:[1,0,1]\n\t"
    "v_pk_fma_f32 v[44:45], v[178:179], v[68:69], v[44:45] op_sel:[0,0,0] op_sel_hi:[1,0,1]\n\t"
    "v_pk_fma_f32 v[42:43], v[180:181], v[68:69], v[42:43] op_sel:[0,1,0] op_sel_hi:[1,1,1]\n\t"
    "v_pk_fma_f32 v[46:47], v[182:183], v[68:69], v[46:47] op_sel:[0,1,0] op_sel_hi:[1,1,1]\n\t"
    "v_pk_fma_f32 v[40:41], v[184:185], v[70:71], v[40:41] op_sel:[0,0,0] op_sel_hi:[1,0,1]\n\t"
    "v_pk_fma_f32 v[44:45], v[186:187], v[70:71], v[44:45] op_sel:[0,0,0] op_sel_hi:[1,0,1]\n\t"
    "v_pk_fma_f32 v[42:43], v[188:189], v[70:71], v[42:43] op_sel:[0,1,0] op_sel_hi:[1,1,1]\n\t"
    "v_pk_fma_f32 v[46:47], v[190:191], v[70:71], v[46:47] op_sel:[0,1,0] op_sel_hi:[1,1,1]\n\t"
    "v_pk_fma_f32 v[40:41], v[192:193], v[72:73], v[40:41] op_sel:[0,0,0] op_sel_hi:[1,0,1]\n\t"
    "v_pk_fma_f32 v[44:45], v[194:195], v[72:73], v[44:45] op_sel:[0,0,0] op_sel_hi:[1,0,1]\n\t"
    "v_pk_fma_f32 v[42:43], v[196:197], v[72:73], v[42:43] op_sel:[0,1,0] op_sel_hi:[1,1,1]\n\t"
    "v_pk_fma_f32 v[46:47], v[198:199], v[72:73], v[46:47] op_sel:[0,1,0] op_sel_hi:[1,1,1]\n\t"
    "v_pk_fma_f32 v[40:41], v[200:201], v[74:75], v[40:41] op_sel:[0,0,0] op_sel_hi:[1,0,1]\n\t"
    "v_pk_fma_f32 v[44:45], v[202:203], v[74:75], v[44:45] op_sel:[0,0,0] op_sel_hi:[1,0,1]\n\t"
    "v_pk_fma_f32 v[42:43], v[204:205], v[74:75], v[42:43] op_sel:[0,1,0] op_sel_hi:[1,1,1]\n\t"
    "v_pk_fma_f32 v[46:47], v[206:207], v[74:75], v[46:47] op_sel:[0,1,0] op_sel_hi:[1,1,1]\n\t"
    "v_pk_fma_f32 v[40:41], v[208:209], v[76:77], v[40:41] op_sel:[0,0,0] op_sel_hi:[1,0,1]\n\t"
    "v_pk_fma_f32 v[44:45], v[210:211], v[76:77], v[44:45] op_sel:[0,0,0] op_sel_hi:[1,0,1]\n\t"
    "v_pk_fma_f32 v[42:43], v[212:213], v[76:77], v[42:43] op_sel:[0,1,0] op_sel_hi:[1,1,1]\n\t"
    "v_pk_fma_f32 v[46:47], v[214:215], v[76:77], v[46:47] op_sel:[0,1,0] op_sel_hi:[1,1,1]\n\t"
    "v_pk_fma_f32 v[40:41], v[216:217], v[78:79], v[40:41] op_sel:[0,0,0] op_sel_hi:[1,0,1]\n\t"
    "v_pk_fma_f32 v[44:45], v[218:219], v[78:79], v[44:45] op_sel:[0,0,0] op_sel_hi:[1,0,1]\n\t"
    "v_pk_fma_f32 v[42:43], v[220:221], v[78:79], v[42:43] op_sel:[0,1,0] op_sel_hi:[1,1,1]\n\t"
    "v_pk_fma_f32 v[46:47], v[222:223], v[78:79], v[46:47] op_sel:[0,1,0] op_sel_hi:[1,1,1]\n\t"
    // reduce: {aI,aF} in v[40:41], {aG,aO} in v[44:45] (pre-scaled exp2 args)
    "v_pk_add_f32 v[40:41], v[40:41], v[42:43]\n\t"
    "v_pk_add_f32 v[44:45], v[44:45], v[46:47]\n\t"
    "v_exp_f32 v80, v40\n\t"
    "v_exp_f32 v81, v41\n\t"
    "v_exp_f32 v82, v44\n\t"
    "v_exp_f32 v83, v45\n\t"
    "v_add_f32 v80, 1.0, v80\n\t"
    "v_add_f32 v81, 1.0, v81\n\t"
    "v_add_f32 v82, 1.0, v82\n\t"
    "v_add_f32 v83, 1.0, v83\n\t"
    "v_rcp_f32 v80, v80\n\t"              // sig(i)
    "v_rcp_f32 v81, v81\n\t"              // sig(f)
    "v_rcp_f32 v82, v82\n\t"              // -> tanh(g)
    "v_rcp_f32 v83, v83\n\t"              // sig(o)
    "v_fma_f32 v82, 2.0, v82, -1.0\n\t"   // tanh(g)
    "v_mul_f32 v84, v80, v82\n\t"         // sig(i)*tanh(g)
    "v_fma_f32 %[c], v81, %[c], v84\n\t"  // c = sig(f)*c + sig(i)*tanh(g)
    "v_mul_f32 v85, 0xc038aa3b, %[c]\n\t" // -2*log2e * c
    "v_exp_f32 v85, v85\n\t"
    "s_nop 1\n\t"
    "v_add_f32 v85, 1.0, v85\n\t"
    "v_rcp_f32 v85, v85\n\t"
    "s_nop 1\n\t"
    "v_fma_f32 v85, 2.0, v85, -1.0\n\t"   // tanh(c)
    "v_mul_f32 %[h], v83, v85\n\t"        // h = sig(o)*tanh(c)
    "buffer_store_dword %[h], %[voff], %[osrd], 0 offen\n\t"
    "v_add_u32 %[voff], 0xa00, %[voff]\n\t"
    "s_sub_u32 s20, s20, 1\n\t"
    "s_cmp_lg_u32 s20, 0\n\t"
    "s_cbranch_scc1 Lstep%=\n\t"
    "s_sub_u32 s21, s21, 1\n\t"
    "s_cmp_lg_u32 s21, 0\n\t"
    "s_cbranch_scc1 Lchunk%=\n\t"
    : [h]"+v"(h), [c]"+v"(c), [voff]"+v"(voff), [xvoff]"+v"(xvoff)
    : [laddr]"v"(laddr), [hrd]"v"(hrd), [xw]"v"(xw), [xrb]"v"(xrb),
      [wrd]"v"(wrd),
      [w11IF]"v"(w11IF), [w21IF]"v"(w21IF), [bsIF]"v"(bsIF),
      [w11GO]"v"(w11GO), [w21GO]"v"(w21GO), [bsGO]"v"(bsGO),
      [xsrd]"s"(xsrd), [osrd]"s"(osrd), [sfd]"s"(sfd)
    : "memory", "scc", "s20", "s21", "s22", "s23",
      "v33","v36","v37","v38","v39",
      "v40","v41","v42","v43","v44","v45","v46","v47",
      "v48","v49","v50","v51","v52","v53","v54","v55",
      "v56","v57","v58","v59","v60","v61","v62","v63",
      "v64","v65","v66","v67","v68","v69","v70","v71",
      "v72","v73","v74","v75","v76","v77","v78","v79",
      "v80","v81","v82","v83","v84","v85","v88","v89",
      "v96","v97","v98","v99","v100","v101","v102","v103",
      "v104","v105","v106","v107","v108","v109","v110","v111",
      "v112","v113","v114","v115","v116","v117","v118","v119",
      "v120","v121","v122","v123","v124","v125","v126","v127",
      "v128","v129","v130","v131","v132","v133","v134","v135",
      "v136","v137","v138","v139","v140","v141","v142","v143",
      "v144","v145","v146","v147","v148","v149","v150","v151",
      "v152","v153","v154","v155","v156","v157","v158","v159",
      "v160","v161","v162","v163","v164","v165","v166","v167",
      "v168","v169","v170","v171","v172","v173","v174","v175",
      "v176","v177","v178","v179","v180","v181","v182","v183",
      "v184","v185","v186","v187","v188","v189","v190","v191",
      "v192","v193","v194","v195","v196","v197","v198","v199",
      "v200","v201","v202","v203","v204","v205","v206","v207",
      "v208","v209","v210","v211","v212","v213","v214","v215",
      "v216","v217","v218","v219","v220","v221","v222","v223");

  out[BN * TT * HN + b * HN + col] = h;             // h_t
  out[BN * TT * HN + BN * HN + b * HN + col] = c;   // c_t
}

extern "C" void kernel_launch(void* const* d_in, const int* in_sizes, int n_in,
                              void* d_out, int out_size, void* d_ws, size_t ws_size,
                              hipStream_t stream) {
  (void)in_sizes; (void)n_in; (void)d_ws; (void)ws_size; (void)out_size;
  const float* x  = (const float*)d_in[0];
  const float* Ui = (const float*)d_in[1];
  const float* Vi = (const float*)d_in[2];
  const float* bi = (const float*)d_in[3];
  const float* Uf = (const float*)d_in[4];
  const float* Vf = (const float*)d_in[5];
  const float* bf = (const float*)d_in[6];
  const float* Uc = (const float*)d_in[7];
  const float* Vc = (const float*)d_in[8];
  const float* bc = (const float*)d_in[9];
  const float* Uo = (const float*)d_in[10];
  const float* Vo = (const float*)d_in[11];
  const float* bo = (const float*)d_in[12];
  float* out = (float*)d_out;

  dim3 grid(1280);  // 20 blocks x 64 batch-pairs; 2 units per wave
  dim3 block(64);
  hipLaunchKernelGGL(lstm_kernel, grid, block, 0, stream,
                     x, Ui, Vi, bi, Uf, Vf, bf, Uc, Vc, bc, Uo, Vo, bo, out);
}